// Round 3
// baseline (277.608 us; speedup 1.0000x reference)
//
#include <hip/hip_runtime.h>
#include <hip/hip_bf16.h>

// MHA forward, MI355X gfx950.
// B=2, S=2048, D=1024, H=16, DK=64.
// d_in: 0 q,1 k,2 v,3 mask,4 w_q,5 b_q,6 w_k,7 b_k,8 w_v,9 b_v,10 w_o,11 b_o
// d_out: [out (2,2048,1024) f32][attn_weights (2,16,2048,2048) f32]
//
// Frag-major bf16 everywhere (one MFMA A/B fragment = 16x32 = 1KB, lane l's
// 16B at offset l*16). Attention uses SWAPPED QK^T (mfma(K,Q)) so each lane
// owns one P-row with consecutive-k reg quads: f32x4 P stores, scalar-row
// softmax, and in-register P->A-frag redistribution for PV (no LDS P).
//
// ws layout:
//   A0 (8.39MB): qbf  -> khf      A1: kbf -> vhf      A2: vbf -> ctxf
//   A3 (8.39MB): qhf              W (4x2MB): wqf wkf wvf wof   flag (4B)

#define DEVI __device__ __forceinline__

typedef short bf16x8 __attribute__((ext_vector_type(8)));
typedef float f32x4  __attribute__((ext_vector_type(4)));
typedef unsigned short u16x4 __attribute__((ext_vector_type(4)));
typedef unsigned int u32x4 __attribute__((ext_vector_type(4)));

static constexpr int S = 2048;
static constexpr int DK = 64;
static constexpr size_t A_ELEMS = 4194304;   // 4096*1024
static constexpr size_t W_ELEMS = 1048576;   // 1024*1024
static constexpr size_t BH_ELEMS = 131072;   // 2048*64

DEVI unsigned short f2bf(float f) {
  unsigned u = __float_as_uint(f);
  unsigned r = u + 0x7fffu + ((u >> 16) & 1u);  // RNE
  return (unsigned short)(r >> 16);
}

// ---------------------------------------------------------------- mask flag
__global__ void flag_init_kernel(int* flag) { *flag = 1; }

__global__ void mask_and_kernel(const int* __restrict__ mask, int* __restrict__ flag) {
  const int4* m4 = (const int4*)mask;
  int acc = ~0;
  int stride = gridDim.x * blockDim.x;
  for (int i = blockIdx.x * blockDim.x + threadIdx.x; i < S * S / 4; i += stride) {
    int4 v = m4[i];
    acc &= v.x & v.y & v.z & v.w;
  }
  if (acc == 0) atomicAnd(flag, 0);
}

// ---------------------------------------------------------------- converts
__global__ __launch_bounds__(256) void convert_a(const float* __restrict__ q,
                                                 const float* __restrict__ k,
                                                 const float* __restrict__ v,
                                                 unsigned short* __restrict__ qb,
                                                 unsigned short* __restrict__ kb,
                                                 unsigned short* __restrict__ vb) {
  const int z = blockIdx.y;
  const float* src = (z == 0) ? q : (z == 1) ? k : v;
  unsigned short* dst = (z == 0) ? qb : (z == 1) ? kb : vb;
  const int t = blockIdx.x * 256 + threadIdx.x;
  const int r = t >> 7, i0 = (t & 127) << 3;
  const float4* s4 = (const float4*)(src + (size_t)r * 1024 + i0);
  float4 a = s4[0], b = s4[1];
  bf16x8 pk;
  pk[0] = (short)f2bf(a.x); pk[1] = (short)f2bf(a.y);
  pk[2] = (short)f2bf(a.z); pk[3] = (short)f2bf(a.w);
  pk[4] = (short)f2bf(b.x); pk[5] = (short)f2bf(b.y);
  pk[6] = (short)f2bf(b.z); pk[7] = (short)f2bf(b.w);
  size_t addr = ((size_t)((r >> 4) * 32 + (i0 >> 5)) << 9) + (((i0 >> 3) & 3) << 7) + ((r & 15) << 3);
  *(bf16x8*)(dst + addr) = pk;
}

__global__ __launch_bounds__(256) void convert_w(const float* __restrict__ w0,
                                                 const float* __restrict__ w1,
                                                 const float* __restrict__ w2,
                                                 const float* __restrict__ w3,
                                                 unsigned short* __restrict__ dstbase) {
  const int z = blockIdx.y;
  const float* src = (z == 0) ? w0 : (z == 1) ? w1 : (z == 2) ? w2 : w3;
  unsigned short* dst = dstbase + (size_t)z * W_ELEMS;
  const int t = blockIdx.x * 256 + threadIdx.x;
  const int o = t >> 7, i0 = (t & 127) << 3;
  const float4* s4 = (const float4*)(src + (size_t)o * 1024 + i0);
  float4 a = s4[0], b = s4[1];
  bf16x8 pk;
  pk[0] = (short)f2bf(a.x); pk[1] = (short)f2bf(a.y);
  pk[2] = (short)f2bf(a.z); pk[3] = (short)f2bf(a.w);
  pk[4] = (short)f2bf(b.x); pk[5] = (short)f2bf(b.y);
  pk[6] = (short)f2bf(b.z); pk[7] = (short)f2bf(b.w);
  size_t addr = ((size_t)((o >> 4) * 32 + (i0 >> 5)) << 9) + (((i0 >> 3) & 3) << 7) + ((o & 15) << 3);
  *(bf16x8*)(dst + addr) = pk;
}

// ---------------------------------------------------------------- projection GEMM (frag-direct)
template <int MODE>
__global__ __launch_bounds__(256) void proj_frag(const unsigned short* __restrict__ Af,
                                                 const unsigned short* __restrict__ Wf,
                                                 const float* __restrict__ bias,
                                                 void* __restrict__ outp, float scale) {
  const int t = threadIdx.x, l = t & 63, w = t >> 6;
  const int wr = w >> 1, wc = w & 1;
  const int bx = blockIdx.x, by = blockIdx.y;

  const unsigned short* a0 = Af + (((size_t)(bx * 8 + wr * 4) * 32) << 9) + l * 8;
  const unsigned short* b0 = Wf + (((size_t)(by * 4 + wc * 2) * 32) << 9) + l * 8;

  f32x4 acc[4][2];
#pragma unroll
  for (int m = 0; m < 4; ++m)
#pragma unroll
    for (int n = 0; n < 2; ++n) acc[m][n] = {0.f, 0.f, 0.f, 0.f};

#pragma unroll 4
  for (int c = 0; c < 32; ++c) {
    bf16x8 af[4], bfr[2];
#pragma unroll
    for (int m = 0; m < 4; ++m)
      af[m] = *(const bf16x8*)(a0 + (((size_t)(m * 32 + c)) << 9));
#pragma unroll
    for (int n = 0; n < 2; ++n)
      bfr[n] = *(const bf16x8*)(b0 + (((size_t)(n * 32 + c)) << 9));
#pragma unroll
    for (int n = 0; n < 2; ++n)
#pragma unroll
      for (int m = 0; m < 4; ++m)
        acc[m][n] = __builtin_amdgcn_mfma_f32_16x16x32_bf16(af[m], bfr[n], acc[m][n], 0, 0, 0);
  }

  const int l4 = (l >> 4) << 2, cl = l & 15;
#pragma unroll
  for (int n = 0; n < 2; ++n) {
    const int gc = by * 64 + wc * 32 + n * 16 + cl;
    const float bi = bias[gc];
#pragma unroll
    for (int m = 0; m < 4; ++m) {
      const int gr0 = bx * 128 + wr * 64 + m * 16 + l4;
      if (MODE == 2) {
        float* o = (float*)outp;
#pragma unroll
        for (int j = 0; j < 4; ++j)
          o[(size_t)(gr0 + j) * 1024 + gc] = acc[m][n][j] + bi;
      } else {
        const int b = gr0 >> 11, s0 = gr0 & 2047, h = gc >> 6, d = gc & 63;
        const size_t base = (size_t)(b * 16 + h) * BH_ELEMS;
        unsigned short* o = (unsigned short*)outp;
        if (MODE == 0) {
#pragma unroll
          for (int j = 0; j < 4; ++j) {
            const int s = s0 + j;
            size_t addr = base + ((size_t)((s >> 4) * 2 + (d >> 5)) << 9) +
                          (((d >> 3) & 3) << 7) + ((s & 15) << 3) + (d & 7);
            o[addr] = f2bf((acc[m][n][j] + bi) * scale);
          }
        } else {
          size_t addr = base + ((size_t)((s0 >> 5) * 4 + (d >> 4)) << 9) +
                        (((s0 >> 3) & 3) << 7) + ((d & 15) << 3) + (s0 & 7);
          u16x4 pk;
#pragma unroll
          for (int j = 0; j < 4; ++j) pk[j] = f2bf(acc[m][n][j] + bi);
          *(u16x4*)(o + addr) = pk;
        }
      }
    }
  }
}

// ---------------------------------------------------------------- attention v3
// One block = one (b,h) x 16 query rows. 512 thr / 8 waves.
// Wave w owns contiguous k-range [w*256, w*256+256). Swapped QK^T: lane l
// owns row q = l&15, k = w*256 + ct*16 + 4*(l>>4) + j.
__global__ __launch_bounds__(512, 4) void attn_v3(const unsigned short* __restrict__ Qf,
                                                  const unsigned short* __restrict__ Kf,
                                                  const unsigned short* __restrict__ Vf,
                                                  const int* __restrict__ mask,
                                                  const int* __restrict__ flag,
                                                  float* __restrict__ Pout,
                                                  unsigned short* __restrict__ ctxf) {
  __shared__ float red[8 * 1024];   // 32 KB ctx cross-wave reduce
  __shared__ float rred[8][16];

  const int t = threadIdx.x, l = t & 63, w = t >> 6;
  const int bid = blockIdx.x;
  const int swz = (bid & 7) * 512 + (bid >> 3);   // bijective: 4096 % 8 == 0
  const int bh = swz >> 7, rt = swz & 127;
  const int q0 = rt * 16;
  const int g = l >> 4, q = l & 15;

  const unsigned short* qf = Qf + (size_t)bh * BH_ELEMS + l * 8;
  const unsigned short* kf = Kf + (size_t)bh * BH_ELEMS + l * 8;
  const unsigned short* vf = Vf + (size_t)bh * BH_ELEMS + l * 8;

  const bf16x8 aq0 = *(const bf16x8*)(qf + ((size_t)(rt * 2) << 9));
  const bf16x8 aq1 = *(const bf16x8*)(qf + ((size_t)(rt * 2 + 1) << 9));

  // ---- scores (swapped: A=K rows=k, B=Q cols=q)
  f32x4 sacc[16];
#pragma unroll
  for (int ct = 0; ct < 16; ++ct) {
    const int gi = w * 16 + ct;
    bf16x8 ak0 = *(const bf16x8*)(kf + ((size_t)(gi * 2) << 9));
    bf16x8 ak1 = *(const bf16x8*)(kf + ((size_t)(gi * 2 + 1) << 9));
    f32x4 s = {0.f, 0.f, 0.f, 0.f};
    s = __builtin_amdgcn_mfma_f32_16x16x32_bf16(ak0, aq0, s, 0, 0, 0);
    s = __builtin_amdgcn_mfma_f32_16x16x32_bf16(ak1, aq1, s, 0, 0, 0);
    sacc[ct] = s;
    if ((ct & 3) == 3) __builtin_amdgcn_sched_barrier(0);
  }

  // ---- mask slow path
  if (*flag == 0) {
#pragma unroll
    for (int ct = 0; ct < 16; ++ct) {
      const int col = w * 256 + ct * 16 + g * 4;
#pragma unroll
      for (int j = 0; j < 4; ++j)
        if (mask[(size_t)(q0 + q) * S + col + j] == 0) sacc[ct][j] = -1e9f;
    }
  }

  // ---- softmax over the lane's single row (scores are pre-scaled by log2e)
  float m = -1e30f;
#pragma unroll
  for (int ct = 0; ct < 16; ++ct)
#pragma unroll
    for (int j = 0; j < 4; ++j) m = fmaxf(m, sacc[ct][j]);
  m = fmaxf(m, __shfl_xor(m, 16));
  m = fmaxf(m, __shfl_xor(m, 32));
  if (l < 16) rred[w][l] = m;
  __syncthreads();
  float mm = rred[0][q];
#pragma unroll
  for (int ww = 1; ww < 8; ++ww) mm = fmaxf(mm, rred[ww][q]);
  __syncthreads();

  float z = 0.f;
#pragma unroll
  for (int ct = 0; ct < 16; ++ct)
#pragma unroll
    for (int j = 0; j < 4; ++j) {
      float p = exp2f(sacc[ct][j] - mm);
      sacc[ct][j] = p;
      z += p;
    }
  z += __shfl_xor(z, 16);
  z += __shfl_xor(z, 32);
  if (l < 16) rred[w][l] = z;
  __syncthreads();
  float zz = rred[0][q];
#pragma unroll
  for (int ww = 1; ww < 8; ++ww) zz += rred[ww][q];
  const float inv = 1.0f / zz;

  // ---- normalize + vectorized nontemporal P store (row-contiguous)
  float* prow = Pout + ((size_t)bh * S + q0 + q) * S + w * 256 + g * 4;
#pragma unroll
  for (int ct = 0; ct < 16; ++ct) {
    f32x4 pn = sacc[ct] * inv;
    sacc[ct] = pn;
    __builtin_nontemporal_store(pn, (f32x4*)(prow + ct * 16));
  }

  // ---- PV: in-register P->A-frag redistribution, no LDS
  f32x4 pacc[4];
#pragma unroll
  for (int n = 0; n < 4; ++n) pacc[n] = {0.f, 0.f, 0.f, 0.f};

#pragma unroll
  for (int ks = 0; ks < 8; ++ks) {
    const int t0 = ks * 2, t1 = t0 + 1;
    // pack to bf16 pairs: X = tile t0 (k=t0*16+4g+{0..3}), Y = tile t1
    unsigned Xa, Xb, Ya, Yb;
    asm("v_cvt_pk_bf16_f32 %0, %1, %2" : "=v"(Xa) : "v"(sacc[t0][0]), "v"(sacc[t0][1]));
    asm("v_cvt_pk_bf16_f32 %0, %1, %2" : "=v"(Xb) : "v"(sacc[t0][2]), "v"(sacc[t0][3]));
    asm("v_cvt_pk_bf16_f32 %0, %1, %2" : "=v"(Ya) : "v"(sacc[t1][0]), "v"(sacc[t1][1]));
    asm("v_cvt_pk_bf16_f32 %0, %1, %2" : "=v"(Yb) : "v"(sacc[t1][2]), "v"(sacc[t1][3]));
    // butterfly round 1 (xor 32): lower halves keep X, receive partner X;
    // upper keep Y, receive partner Y.
    const bool lo2 = (g < 2);
    unsigned sel_a = lo2 ? Ya : Xa, sel_b = lo2 ? Yb : Xb;
    unsigned kept_a = lo2 ? Xa : Ya, kept_b = lo2 ? Xb : Yb;
    unsigned r1_a = (unsigned)__shfl_xor((int)sel_a, 32);
    unsigned r1_b = (unsigned)__shfl_xor((int)sel_b, 32);
    // state: g0{kept=X0,r1=X2} g1{X1,X3} g2{Y2,Y0} g3{Y3,Y1}
    // round 2 (xor 16): g1,g2 send kept; g0,g3 send r1.
    const bool mid = (g == 1) || (g == 2);
    unsigned s2_a = mid ? kept_a : r1_a;
    unsigned s2_b = mid ? kept_b : r1_b;
    unsigned r2_a = (unsigned)__shfl_xor((int)s2_a, 16);
    unsigned r2_b = (unsigned)__shfl_xor((int)s2_b, 16);
    // finals per group: g0:[kept,r2] g1:[r2,r1] g2:[r1,r2] g3:[r2,kept]
    u32x4 fr;
    fr[0] = (g == 0) ? kept_a : ((g == 2) ? r1_a : r2_a);
    fr[1] = (g == 0) ? kept_b : ((g == 2) ? r1_b : r2_b);
    fr[2] = (g == 3) ? kept_a : ((g == 1) ? r1_a : r2_a);
    fr[3] = (g == 3) ? kept_b : ((g == 1) ? r1_b : r2_b);
    bf16x8 ap = __builtin_bit_cast(bf16x8, fr);
    const int kbi = w * 8 + ks;
#pragma unroll
    for (int n = 0; n < 4; ++n) {
      bf16x8 bv = *(const bf16x8*)(vf + ((size_t)(kbi * 4 + n) << 9));
      pacc[n] = __builtin_amdgcn_mfma_f32_16x16x32_bf16(ap, bv, pacc[n], 0, 0, 0);
    }
    __builtin_amdgcn_sched_barrier(0);
  }

  // ---- cross-wave K-slice reduce (f32 [8][1024]) -> ctx A-frag out
#pragma unroll
  for (int n = 0; n < 4; ++n)
#pragma unroll
    for (int j = 0; j < 4; ++j)
      red[w * 1024 + (g * 4 + j) * 64 + n * 16 + q] = pacc[n][j];
  __syncthreads();
  const int b = bh >> 4, h = bh & 15;
#pragma unroll
  for (int i = 0; i < 2; ++i) {
    int idx = t * 2 + i;
    float s = red[idx];
#pragma unroll
    for (int ww = 1; ww < 8; ++ww) s += red[ww * 1024 + idx];
    int qrow = idx >> 6, d = idx & 63;
    size_t addr = ((size_t)((b * 128 + rt) * 32 + h * 2 + (d >> 5)) << 9) +
                  (((d >> 3) & 3) << 7) + (qrow << 3) + (d & 7);
    ctxf[addr] = f2bf(s);
  }
}

// ---------------------------------------------------------------- launch
extern "C" void kernel_launch(void* const* d_in, const int* in_sizes, int n_in,
                              void* d_out, int out_size, void* d_ws, size_t ws_size,
                              hipStream_t stream) {
  const float* q = (const float*)d_in[0];
  const float* k = (const float*)d_in[1];
  const float* v = (const float*)d_in[2];
  const int* mask = (const int*)d_in[3];
  const float* w_q = (const float*)d_in[4];
  const float* b_q = (const float*)d_in[5];
  const float* w_k = (const float*)d_in[6];
  const float* b_k = (const float*)d_in[7];
  const float* w_v = (const float*)d_in[8];
  const float* b_v = (const float*)d_in[9];
  const float* w_o = (const float*)d_in[10];
  const float* b_o = (const float*)d_in[11];

  unsigned short* wsu = (unsigned short*)d_ws;
  unsigned short* A0 = wsu + 0 * A_ELEMS;  // qbf -> khf
  unsigned short* A1 = wsu + 1 * A_ELEMS;  // kbf -> vhf
  unsigned short* A2 = wsu + 2 * A_ELEMS;  // vbf -> ctxf
  unsigned short* A3 = wsu + 3 * A_ELEMS;  // qhf
  unsigned short* Wb = wsu + 4 * A_ELEMS;  // wqf|wkf|wvf|wof
  unsigned short* wqf = Wb + 0 * W_ELEMS;
  unsigned short* wkf = Wb + 1 * W_ELEMS;
  unsigned short* wvf = Wb + 2 * W_ELEMS;
  unsigned short* wof = Wb + 3 * W_ELEMS;
  int* flag = (int*)(Wb + 4 * W_ELEMS);

  float* out_f = (float*)d_out;                  // [4096][1024]
  float* attnW = out_f + (size_t)4096 * 1024;    // [2][16][2048][2048]

  flag_init_kernel<<<1, 1, 0, stream>>>(flag);
  mask_and_kernel<<<1024, 256, 0, stream>>>(mask, flag);

  convert_a<<<dim3(2048, 3), 256, 0, stream>>>(q, k, v, A0, A1, A2);
  convert_w<<<dim3(512, 4), 256, 0, stream>>>(w_q, w_k, w_v, w_o, Wb);

  // qscale folds 1/sqrt(64) AND log2(e) (softmax done in exp2 domain).
  const float qscale = 0.125f * 1.4426950408889634f;
  proj_frag<0><<<dim3(32, 16), 256, 0, stream>>>(A0, wqf, b_q, (void*)A3, qscale);  // Q
  proj_frag<0><<<dim3(32, 16), 256, 0, stream>>>(A1, wkf, b_k, (void*)A0, 1.0f);    // K
  proj_frag<1><<<dim3(32, 16), 256, 0, stream>>>(A2, wvf, b_v, (void*)A1, 1.0f);    // V

  attn_v3<<<4096, 512, 0, stream>>>(A3, A0, A1, mask, flag, attnW, A2);

  proj_frag<2><<<dim3(32, 16), 256, 0, stream>>>(A2, wof, b_o, (void*)d_out, 1.0f); // O
}

// Round 4
// 273.055 us; speedup vs baseline: 1.0167x; 1.0167x over previous
//
#include <hip/hip_runtime.h>
#include <hip/hip_bf16.h>

// MHA forward, MI355X gfx950.
// B=2, S=2048, D=1024, H=16, DK=64.
// d_in: 0 q,1 k,2 v,3 mask,4 w_q,5 b_q,6 w_k,7 b_k,8 w_v,9 b_v,10 w_o,11 b_o
// d_out: [out (2,2048,1024) f32][attn_weights (2,16,2048,2048) f32]
//
// Frag-major bf16 everywhere (one MFMA A/B fragment = 16x32 = 1KB, lane l's
// 16B at offset l*16). Attention uses SWAPPED QK^T (mfma(K,Q)) so each lane
// owns one P-row. v4: phase-separated tail — normalize+store, then pack all
// P->bf16 A-frags in-register (butterfly), then a pure MFMA PV stream.
//
// ws layout:
//   A0 (8.39MB): qbf  -> khf      A1: kbf -> vhf      A2: vbf -> ctxf
//   A3 (8.39MB): qhf              W (4x2MB): wqf wkf wvf wof   flag (4B)

#define DEVI __device__ __forceinline__

typedef short bf16x8 __attribute__((ext_vector_type(8)));
typedef float f32x4  __attribute__((ext_vector_type(4)));
typedef unsigned short u16x4 __attribute__((ext_vector_type(4)));
typedef unsigned int u32x4 __attribute__((ext_vector_type(4)));

static constexpr int S = 2048;
static constexpr int DK = 64;
static constexpr size_t A_ELEMS = 4194304;   // 4096*1024
static constexpr size_t W_ELEMS = 1048576;   // 1024*1024
static constexpr size_t BH_ELEMS = 131072;   // 2048*64

DEVI unsigned short f2bf(float f) {
  unsigned u = __float_as_uint(f);
  unsigned r = u + 0x7fffu + ((u >> 16) & 1u);  // RNE
  return (unsigned short)(r >> 16);
}

// ---------------------------------------------------------------- mask flag
__global__ void flag_init_kernel(int* flag) { *flag = 1; }

__global__ void mask_and_kernel(const int* __restrict__ mask, int* __restrict__ flag) {
  const int4* m4 = (const int4*)mask;
  int acc = ~0;
  int stride = gridDim.x * blockDim.x;
  for (int i = blockIdx.x * blockDim.x + threadIdx.x; i < S * S / 4; i += stride) {
    int4 v = m4[i];
    acc &= v.x & v.y & v.z & v.w;
  }
  if (acc == 0) atomicAnd(flag, 0);
}

// ---------------------------------------------------------------- converts
__global__ __launch_bounds__(256) void convert_a(const float* __restrict__ q,
                                                 const float* __restrict__ k,
                                                 const float* __restrict__ v,
                                                 unsigned short* __restrict__ qb,
                                                 unsigned short* __restrict__ kb,
                                                 unsigned short* __restrict__ vb) {
  const int z = blockIdx.y;
  const float* src = (z == 0) ? q : (z == 1) ? k : v;
  unsigned short* dst = (z == 0) ? qb : (z == 1) ? kb : vb;
  const int t = blockIdx.x * 256 + threadIdx.x;
  const int r = t >> 7, i0 = (t & 127) << 3;
  const float4* s4 = (const float4*)(src + (size_t)r * 1024 + i0);
  float4 a = s4[0], b = s4[1];
  bf16x8 pk;
  pk[0] = (short)f2bf(a.x); pk[1] = (short)f2bf(a.y);
  pk[2] = (short)f2bf(a.z); pk[3] = (short)f2bf(a.w);
  pk[4] = (short)f2bf(b.x); pk[5] = (short)f2bf(b.y);
  pk[6] = (short)f2bf(b.z); pk[7] = (short)f2bf(b.w);
  size_t addr = ((size_t)((r >> 4) * 32 + (i0 >> 5)) << 9) + (((i0 >> 3) & 3) << 7) + ((r & 15) << 3);
  *(bf16x8*)(dst + addr) = pk;
}

__global__ __launch_bounds__(256) void convert_w(const float* __restrict__ w0,
                                                 const float* __restrict__ w1,
                                                 const float* __restrict__ w2,
                                                 const float* __restrict__ w3,
                                                 unsigned short* __restrict__ dstbase) {
  const int z = blockIdx.y;
  const float* src = (z == 0) ? w0 : (z == 1) ? w1 : (z == 2) ? w2 : w3;
  unsigned short* dst = dstbase + (size_t)z * W_ELEMS;
  const int t = blockIdx.x * 256 + threadIdx.x;
  const int o = t >> 7, i0 = (t & 127) << 3;
  const float4* s4 = (const float4*)(src + (size_t)o * 1024 + i0);
  float4 a = s4[0], b = s4[1];
  bf16x8 pk;
  pk[0] = (short)f2bf(a.x); pk[1] = (short)f2bf(a.y);
  pk[2] = (short)f2bf(a.z); pk[3] = (short)f2bf(a.w);
  pk[4] = (short)f2bf(b.x); pk[5] = (short)f2bf(b.y);
  pk[6] = (short)f2bf(b.z); pk[7] = (short)f2bf(b.w);
  size_t addr = ((size_t)((o >> 4) * 32 + (i0 >> 5)) << 9) + (((i0 >> 3) & 3) << 7) + ((o & 15) << 3);
  *(bf16x8*)(dst + addr) = pk;
}

// ---------------------------------------------------------------- projection GEMM (frag-direct)
template <int MODE>
__global__ __launch_bounds__(256) void proj_frag(const unsigned short* __restrict__ Af,
                                                 const unsigned short* __restrict__ Wf,
                                                 const float* __restrict__ bias,
                                                 void* __restrict__ outp, float scale) {
  const int t = threadIdx.x, l = t & 63, w = t >> 6;
  const int wr = w >> 1, wc = w & 1;
  const int bx = blockIdx.x, by = blockIdx.y;

  const unsigned short* a0 = Af + (((size_t)(bx * 8 + wr * 4) * 32) << 9) + l * 8;
  const unsigned short* b0 = Wf + (((size_t)(by * 4 + wc * 2) * 32) << 9) + l * 8;

  f32x4 acc[4][2];
#pragma unroll
  for (int m = 0; m < 4; ++m)
#pragma unroll
    for (int n = 0; n < 2; ++n) acc[m][n] = {0.f, 0.f, 0.f, 0.f};

#pragma unroll 4
  for (int c = 0; c < 32; ++c) {
    bf16x8 af[4], bfr[2];
#pragma unroll
    for (int m = 0; m < 4; ++m)
      af[m] = *(const bf16x8*)(a0 + (((size_t)(m * 32 + c)) << 9));
#pragma unroll
    for (int n = 0; n < 2; ++n)
      bfr[n] = *(const bf16x8*)(b0 + (((size_t)(n * 32 + c)) << 9));
#pragma unroll
    for (int n = 0; n < 2; ++n)
#pragma unroll
      for (int m = 0; m < 4; ++m)
        acc[m][n] = __builtin_amdgcn_mfma_f32_16x16x32_bf16(af[m], bfr[n], acc[m][n], 0, 0, 0);
  }

  const int l4 = (l >> 4) << 2, cl = l & 15;
#pragma unroll
  for (int n = 0; n < 2; ++n) {
    const int gc = by * 64 + wc * 32 + n * 16 + cl;
    const float bi = bias[gc];
#pragma unroll
    for (int m = 0; m < 4; ++m) {
      const int gr0 = bx * 128 + wr * 64 + m * 16 + l4;
      if (MODE == 2) {
        float* o = (float*)outp;
#pragma unroll
        for (int j = 0; j < 4; ++j)
          o[(size_t)(gr0 + j) * 1024 + gc] = acc[m][n][j] + bi;
      } else {
        const int b = gr0 >> 11, s0 = gr0 & 2047, h = gc >> 6, d = gc & 63;
        const size_t base = (size_t)(b * 16 + h) * BH_ELEMS;
        unsigned short* o = (unsigned short*)outp;
        if (MODE == 0) {
#pragma unroll
          for (int j = 0; j < 4; ++j) {
            const int s = s0 + j;
            size_t addr = base + ((size_t)((s >> 4) * 2 + (d >> 5)) << 9) +
                          (((d >> 3) & 3) << 7) + ((s & 15) << 3) + (d & 7);
            o[addr] = f2bf((acc[m][n][j] + bi) * scale);
          }
        } else {
          size_t addr = base + ((size_t)((s0 >> 5) * 4 + (d >> 4)) << 9) +
                        (((s0 >> 3) & 3) << 7) + ((d & 15) << 3) + (s0 & 7);
          u16x4 pk;
#pragma unroll
          for (int j = 0; j < 4; ++j) pk[j] = f2bf(acc[m][n][j] + bi);
          *(u16x4*)(o + addr) = pk;
        }
      }
    }
  }
}

// ---------------------------------------------------------------- attention v4
// One block = one (b,h) x 16 query rows. 512 thr / 8 waves.
// Wave w owns contiguous k-range [w*256, w*256+256). Swapped QK^T: lane l
// owns row q = l&15, k = w*256 + ct*16 + 4*(l>>4) + j.
// Phases: scores -> softmax -> normalize+store -> pack (butterfly) -> PV.
__global__ __launch_bounds__(512, 4) void attn_v4(const unsigned short* __restrict__ Qf,
                                                  const unsigned short* __restrict__ Kf,
                                                  const unsigned short* __restrict__ Vf,
                                                  const int* __restrict__ mask,
                                                  const int* __restrict__ flag,
                                                  float* __restrict__ Pout,
                                                  unsigned short* __restrict__ ctxf) {
  __shared__ float red[8 * 1024];   // 32 KB ctx cross-wave reduce
  __shared__ float rred[8][16];

  const int t = threadIdx.x, l = t & 63, w = t >> 6;
  const int bid = blockIdx.x;
  const int swz = (bid & 7) * 512 + (bid >> 3);   // bijective: 4096 % 8 == 0
  const int bh = swz >> 7, rt = swz & 127;
  const int q0 = rt * 16;
  const int g = l >> 4, q = l & 15;

  const unsigned short* qf = Qf + (size_t)bh * BH_ELEMS + l * 8;
  const unsigned short* kf = Kf + (size_t)bh * BH_ELEMS + l * 8;
  const unsigned short* vf = Vf + (size_t)bh * BH_ELEMS + l * 8;

  const bf16x8 aq0 = *(const bf16x8*)(qf + ((size_t)(rt * 2) << 9));
  const bf16x8 aq1 = *(const bf16x8*)(qf + ((size_t)(rt * 2 + 1) << 9));

  // ---- scores (swapped: A=K rows=k, B=Q cols=q)
  f32x4 sacc[16];
#pragma unroll
  for (int ct = 0; ct < 16; ++ct) {
    const int gi = w * 16 + ct;
    bf16x8 ak0 = *(const bf16x8*)(kf + ((size_t)(gi * 2) << 9));
    bf16x8 ak1 = *(const bf16x8*)(kf + ((size_t)(gi * 2 + 1) << 9));
    f32x4 s = {0.f, 0.f, 0.f, 0.f};
    s = __builtin_amdgcn_mfma_f32_16x16x32_bf16(ak0, aq0, s, 0, 0, 0);
    s = __builtin_amdgcn_mfma_f32_16x16x32_bf16(ak1, aq1, s, 0, 0, 0);
    sacc[ct] = s;
    if ((ct & 3) == 3) __builtin_amdgcn_sched_barrier(0);
  }

  // ---- mask slow path
  if (*flag == 0) {
#pragma unroll
    for (int ct = 0; ct < 16; ++ct) {
      const int col = w * 256 + ct * 16 + g * 4;
#pragma unroll
      for (int j = 0; j < 4; ++j)
        if (mask[(size_t)(q0 + q) * S + col + j] == 0) sacc[ct][j] = -1e9f;
    }
  }

  // ---- softmax over the lane's single row (scores pre-scaled by log2e)
  float m = -1e30f;
#pragma unroll
  for (int ct = 0; ct < 16; ++ct)
#pragma unroll
    for (int j = 0; j < 4; ++j) m = fmaxf(m, sacc[ct][j]);
  m = fmaxf(m, __shfl_xor(m, 16));
  m = fmaxf(m, __shfl_xor(m, 32));
  if (l < 16) rred[w][l] = m;
  __syncthreads();
  float mm = rred[0][q];
#pragma unroll
  for (int ww = 1; ww < 8; ++ww) mm = fmaxf(mm, rred[ww][q]);
  __syncthreads();

  float z = 0.f;
#pragma unroll
  for (int ct = 0; ct < 16; ++ct)
#pragma unroll
    for (int j = 0; j < 4; ++j) {
      float p = exp2f(sacc[ct][j] - mm);
      sacc[ct][j] = p;
      z += p;
    }
  z += __shfl_xor(z, 16);
  z += __shfl_xor(z, 32);
  if (l < 16) rred[w][l] = z;
  __syncthreads();
  float zz = rred[0][q];
#pragma unroll
  for (int ww = 1; ww < 8; ++ww) zz += rred[ww][q];
  const float inv = 1.0f / zz;

  // ---- normalize + vectorized nontemporal P store (row-contiguous)
  float* prow = Pout + ((size_t)bh * S + q0 + q) * S + w * 256 + g * 4;
#pragma unroll
  for (int ct = 0; ct < 16; ++ct) {
    f32x4 pn = sacc[ct] * inv;
    sacc[ct] = pn;
    __builtin_nontemporal_store(pn, (f32x4*)(prow + ct * 16));
  }

  // ---- pack ALL P -> bf16 A-frags in-register (butterfly); sacc dies here
  u32x4 pa[8];
#pragma unroll
  for (int ks = 0; ks < 8; ++ks) {
    const int t0 = ks * 2, t1 = t0 + 1;
    unsigned Xa, Xb, Ya, Yb;
    asm("v_cvt_pk_bf16_f32 %0, %1, %2" : "=v"(Xa) : "v"(sacc[t0][0]), "v"(sacc[t0][1]));
    asm("v_cvt_pk_bf16_f32 %0, %1, %2" : "=v"(Xb) : "v"(sacc[t0][2]), "v"(sacc[t0][3]));
    asm("v_cvt_pk_bf16_f32 %0, %1, %2" : "=v"(Ya) : "v"(sacc[t1][0]), "v"(sacc[t1][1]));
    asm("v_cvt_pk_bf16_f32 %0, %1, %2" : "=v"(Yb) : "v"(sacc[t1][2]), "v"(sacc[t1][3]));
    // butterfly round 1 (xor 32)
    const bool lo2 = (g < 2);
    unsigned sel_a = lo2 ? Ya : Xa, sel_b = lo2 ? Yb : Xb;
    unsigned kept_a = lo2 ? Xa : Ya, kept_b = lo2 ? Xb : Yb;
    unsigned r1_a = (unsigned)__shfl_xor((int)sel_a, 32);
    unsigned r1_b = (unsigned)__shfl_xor((int)sel_b, 32);
    // round 2 (xor 16): g1,g2 send kept; g0,g3 send r1.
    const bool mid = (g == 1) || (g == 2);
    unsigned s2_a = mid ? kept_a : r1_a;
    unsigned s2_b = mid ? kept_b : r1_b;
    unsigned r2_a = (unsigned)__shfl_xor((int)s2_a, 16);
    unsigned r2_b = (unsigned)__shfl_xor((int)s2_b, 16);
    // finals per group: g0:[kept,r2] g1:[r2,r1] g2:[r1,r2] g3:[r2,kept]
    u32x4 fr;
    fr[0] = (g == 0) ? kept_a : ((g == 2) ? r1_a : r2_a);
    fr[1] = (g == 0) ? kept_b : ((g == 2) ? r1_b : r2_b);
    fr[2] = (g == 3) ? kept_a : ((g == 1) ? r1_a : r2_a);
    fr[3] = (g == 3) ? kept_b : ((g == 1) ? r1_b : r2_b);
    pa[ks] = fr;
  }

  // ---- PV: pure MFMA stream (V-frag loads free to hoist into pack phase)
  f32x4 pacc[4];
#pragma unroll
  for (int n = 0; n < 4; ++n) pacc[n] = {0.f, 0.f, 0.f, 0.f};

  __builtin_amdgcn_s_setprio(1);
#pragma unroll
  for (int ks = 0; ks < 8; ++ks) {
    const bf16x8 ap = __builtin_bit_cast(bf16x8, pa[ks]);
    const int kbi = w * 8 + ks;
#pragma unroll
    for (int n = 0; n < 4; ++n) {
      bf16x8 bv = *(const bf16x8*)(vf + ((size_t)(kbi * 4 + n) << 9));
      pacc[n] = __builtin_amdgcn_mfma_f32_16x16x32_bf16(ap, bv, pacc[n], 0, 0, 0);
    }
  }
  __builtin_amdgcn_s_setprio(0);

  // ---- cross-wave K-slice reduce (f32 [8][1024]) -> ctx A-frag out
#pragma unroll
  for (int n = 0; n < 4; ++n)
#pragma unroll
    for (int j = 0; j < 4; ++j)
      red[w * 1024 + (g * 4 + j) * 64 + n * 16 + q] = pacc[n][j];
  __syncthreads();
  const int b = bh >> 4, h = bh & 15;
#pragma unroll
  for (int i = 0; i < 2; ++i) {
    int idx = t * 2 + i;
    float s = red[idx];
#pragma unroll
    for (int ww = 1; ww < 8; ++ww) s += red[ww * 1024 + idx];
    int qrow = idx >> 6, d = idx & 63;
    size_t addr = ((size_t)((b * 128 + rt) * 32 + h * 2 + (d >> 5)) << 9) +
                  (((d >> 3) & 3) << 7) + (qrow << 3) + (d & 7);
    ctxf[addr] = f2bf(s);
  }
}

// ---------------------------------------------------------------- launch
extern "C" void kernel_launch(void* const* d_in, const int* in_sizes, int n_in,
                              void* d_out, int out_size, void* d_ws, size_t ws_size,
                              hipStream_t stream) {
  const float* q = (const float*)d_in[0];
  const float* k = (const float*)d_in[1];
  const float* v = (const float*)d_in[2];
  const int* mask = (const int*)d_in[3];
  const float* w_q = (const float*)d_in[4];
  const float* b_q = (const float*)d_in[5];
  const float* w_k = (const float*)d_in[6];
  const float* b_k = (const float*)d_in[7];
  const float* w_v = (const float*)d_in[8];
  const float* b_v = (const float*)d_in[9];
  const float* w_o = (const float*)d_in[10];
  const float* b_o = (const float*)d_in[11];

  unsigned short* wsu = (unsigned short*)d_ws;
  unsigned short* A0 = wsu + 0 * A_ELEMS;  // qbf -> khf
  unsigned short* A1 = wsu + 1 * A_ELEMS;  // kbf -> vhf
  unsigned short* A2 = wsu + 2 * A_ELEMS;  // vbf -> ctxf
  unsigned short* A3 = wsu + 3 * A_ELEMS;  // qhf
  unsigned short* Wb = wsu + 4 * A_ELEMS;  // wqf|wkf|wvf|wof
  unsigned short* wqf = Wb + 0 * W_ELEMS;
  unsigned short* wkf = Wb + 1 * W_ELEMS;
  unsigned short* wvf = Wb + 2 * W_ELEMS;
  unsigned short* wof = Wb + 3 * W_ELEMS;
  int* flag = (int*)(Wb + 4 * W_ELEMS);

  float* out_f = (float*)d_out;                  // [4096][1024]
  float* attnW = out_f + (size_t)4096 * 1024;    // [2][16][2048][2048]

  flag_init_kernel<<<1, 1, 0, stream>>>(flag);
  mask_and_kernel<<<1024, 256, 0, stream>>>(mask, flag);

  convert_a<<<dim3(2048, 3), 256, 0, stream>>>(q, k, v, A0, A1, A2);
  convert_w<<<dim3(512, 4), 256, 0, stream>>>(w_q, w_k, w_v, w_o, Wb);

  // qscale folds 1/sqrt(64) AND log2(e) (softmax done in exp2 domain).
  const float qscale = 0.125f * 1.4426950408889634f;
  proj_frag<0><<<dim3(32, 16), 256, 0, stream>>>(A0, wqf, b_q, (void*)A3, qscale);  // Q
  proj_frag<0><<<dim3(32, 16), 256, 0, stream>>>(A1, wkf, b_k, (void*)A0, 1.0f);    // K
  proj_frag<1><<<dim3(32, 16), 256, 0, stream>>>(A2, wvf, b_v, (void*)A1, 1.0f);    // V

  attn_v4<<<4096, 512, 0, stream>>>(A3, A0, A1, mask, flag, attnW, A2);

  proj_frag<2><<<dim3(32, 16), 256, 0, stream>>>(A2, wof, b_o, (void*)d_out, 1.0f); // O
}

// Round 5
// 263.512 us; speedup vs baseline: 1.0535x; 1.0362x over previous
//
#include <hip/hip_runtime.h>
#include <hip/hip_bf16.h>

// MHA forward, MI355X gfx950.
// B=2, S=2048, D=1024, H=16, DK=64.
// d_in: 0 q,1 k,2 v,3 mask,4 w_q,5 b_q,6 w_k,7 b_k,8 w_v,9 b_v,10 w_o,11 b_o
// d_out: [out (2,2048,1024) f32][attn_weights (2,16,2048,2048) f32]
//
// Frag-major bf16 everywhere (one MFMA A/B fragment = 16x32 = 1KB, lane l's
// 16B at offset l*16). 5 dispatches:
//   memset(flag) -> prologue(converts+mask) -> proj_qkv(z=0..2) -> attn -> proj_o
// Buffer plan (ws = 4 x 8.39MB A + 4 x 2MB W + flag):
//   A0: qbf -> ctxf (attn output)     A1: kbf     A2: vbf     A3: qhf
//   khf/vhf live in d_out's `out` region (scratch until proj_o overwrites it).
// flag semantics: ==0 -> slow masked path. memset to 0xFF each call; mask
// blocks atomicAnd to 0 iff any mask element is zero.

#define DEVI __device__ __forceinline__

typedef short bf16x8 __attribute__((ext_vector_type(8)));
typedef float f32x4  __attribute__((ext_vector_type(4)));
typedef unsigned short u16x4 __attribute__((ext_vector_type(4)));
typedef unsigned int u32x4 __attribute__((ext_vector_type(4)));

static constexpr int S = 2048;
static constexpr int DK = 64;
static constexpr size_t A_ELEMS = 4194304;   // 4096*1024
static constexpr size_t W_ELEMS = 1048576;   // 1024*1024
static constexpr size_t BH_ELEMS = 131072;   // 2048*64

DEVI unsigned short f2bf(float f) {
  unsigned u = __float_as_uint(f);
  unsigned r = u + 0x7fffu + ((u >> 16) & 1u);  // RNE
  return (unsigned short)(r >> 16);
}

// ---------------------------------------------------------------- prologue
// blocks [0,6144): convert q/k/v f32 -> A-frag bf16 (2048 blocks each)
// blocks [6144,8192): convert w_q/w_k/w_v/w_o -> W-frag bf16 (512 each)
// blocks [8192,9216): mask AND-reduce -> flag
__global__ __launch_bounds__(256) void prologue_kernel(
    const float* __restrict__ q, const float* __restrict__ k,
    const float* __restrict__ v, const float* __restrict__ w_q,
    const float* __restrict__ w_k, const float* __restrict__ w_v,
    const float* __restrict__ w_o, const int* __restrict__ mask,
    unsigned short* __restrict__ Abase, unsigned short* __restrict__ Wbase,
    int* __restrict__ flag) {
  const int bid = blockIdx.x;
  if (bid < 8192) {
    const float* src;
    unsigned short* dst;
    int t;
    if (bid < 6144) {
      const int z = bid >> 11;
      src = (z == 0) ? q : (z == 1) ? k : v;
      dst = Abase + (size_t)z * A_ELEMS;
      t = (bid & 2047) * 256 + threadIdx.x;   // 0..524287 over [4096][1024]
    } else {
      const int rz = bid - 6144;
      const int z = rz >> 9;
      src = (z == 0) ? w_q : (z == 1) ? w_k : (z == 2) ? w_v : w_o;
      dst = Wbase + (size_t)z * W_ELEMS;
      t = (rz & 511) * 256 + threadIdx.x;     // 0..131071 over [1024][1024]
    }
    const int r = t >> 7, i0 = (t & 127) << 3;
    const float4* s4 = (const float4*)(src + (size_t)r * 1024 + i0);
    float4 a = s4[0], b = s4[1];
    bf16x8 pk;
    pk[0] = (short)f2bf(a.x); pk[1] = (short)f2bf(a.y);
    pk[2] = (short)f2bf(a.z); pk[3] = (short)f2bf(a.w);
    pk[4] = (short)f2bf(b.x); pk[5] = (short)f2bf(b.y);
    pk[6] = (short)f2bf(b.z); pk[7] = (short)f2bf(b.w);
    size_t addr = ((size_t)((r >> 4) * 32 + (i0 >> 5)) << 9) +
                  (((i0 >> 3) & 3) << 7) + ((r & 15) << 3);
    *(bf16x8*)(dst + addr) = pk;
  } else {
    const int mb = bid - 8192;
    const int4* m4 = (const int4*)mask;
    int acc = ~0;
    for (int i = mb * 256 + threadIdx.x; i < S * S / 4; i += 1024 * 256) {
      int4 vv = m4[i];
      acc &= vv.x & vv.y & vv.z & vv.w;
    }
    if (acc == 0) atomicAnd(flag, 0);
  }
}

// ---------------------------------------------------------------- merged QKV projection
// z=0: qbf(A0) -> qhf(A3), K-style frag, *qscale
// z=1: kbf(A1) -> khf(d_out lo), K-style frag
// z=2: vbf(A2) -> vhf(d_out hi), V-style frag
__global__ __launch_bounds__(256) void proj_qkv(
    const unsigned short* __restrict__ Abase, const unsigned short* __restrict__ Wbase,
    const float* __restrict__ b_q, const float* __restrict__ b_k,
    const float* __restrict__ b_v, unsigned short* __restrict__ qhf,
    unsigned short* __restrict__ khf, unsigned short* __restrict__ vhf,
    float qscale) {
  const int z = blockIdx.z;
  const unsigned short* Af = Abase + (size_t)z * A_ELEMS;
  const unsigned short* Wf = Wbase + (size_t)z * W_ELEMS;
  const float* bias = (z == 0) ? b_q : (z == 1) ? b_k : b_v;
  unsigned short* outp = (z == 0) ? qhf : (z == 1) ? khf : vhf;
  const float scale = (z == 0) ? qscale : 1.0f;

  const int t = threadIdx.x, l = t & 63, w = t >> 6;
  const int wr = w >> 1, wc = w & 1;
  const int bx = blockIdx.x, by = blockIdx.y;

  const unsigned short* a0 = Af + (((size_t)(bx * 8 + wr * 4) * 32) << 9) + l * 8;
  const unsigned short* b0 = Wf + (((size_t)(by * 4 + wc * 2) * 32) << 9) + l * 8;

  f32x4 acc[4][2];
#pragma unroll
  for (int m = 0; m < 4; ++m)
#pragma unroll
    for (int n = 0; n < 2; ++n) acc[m][n] = {0.f, 0.f, 0.f, 0.f};

#pragma unroll 4
  for (int c = 0; c < 32; ++c) {
    bf16x8 af[4], bfr[2];
#pragma unroll
    for (int m = 0; m < 4; ++m)
      af[m] = *(const bf16x8*)(a0 + (((size_t)(m * 32 + c)) << 9));
#pragma unroll
    for (int n = 0; n < 2; ++n)
      bfr[n] = *(const bf16x8*)(b0 + (((size_t)(n * 32 + c)) << 9));
#pragma unroll
    for (int n = 0; n < 2; ++n)
#pragma unroll
      for (int m = 0; m < 4; ++m)
        acc[m][n] = __builtin_amdgcn_mfma_f32_16x16x32_bf16(af[m], bfr[n], acc[m][n], 0, 0, 0);
  }

  const int l4 = (l >> 4) << 2, cl = l & 15;
#pragma unroll
  for (int n = 0; n < 2; ++n) {
    const int gc = by * 64 + wc * 32 + n * 16 + cl;
    const float bi = bias[gc];
#pragma unroll
    for (int m = 0; m < 4; ++m) {
      const int gr0 = bx * 128 + wr * 64 + m * 16 + l4;
      const int b = gr0 >> 11, s0 = gr0 & 2047, h = gc >> 6, d = gc & 63;
      const size_t base = (size_t)(b * 16 + h) * BH_ELEMS;
      if (z != 2) {
#pragma unroll
        for (int j = 0; j < 4; ++j) {
          const int s = s0 + j;
          size_t addr = base + ((size_t)((s >> 4) * 2 + (d >> 5)) << 9) +
                        (((d >> 3) & 3) << 7) + ((s & 15) << 3) + (d & 7);
          outp[addr] = f2bf((acc[m][n][j] + bi) * scale);
        }
      } else {
        size_t addr = base + ((size_t)((s0 >> 5) * 4 + (d >> 4)) << 9) +
                      (((s0 >> 3) & 3) << 7) + ((d & 15) << 3) + (s0 & 7);
        u16x4 pk;
#pragma unroll
        for (int j = 0; j < 4; ++j) pk[j] = f2bf(acc[m][n][j] + bi);
        *(u16x4*)(outp + addr) = pk;
      }
    }
  }
}

// ---------------------------------------------------------------- O projection
__global__ __launch_bounds__(256) void proj_o(const unsigned short* __restrict__ Af,
                                              const unsigned short* __restrict__ Wf,
                                              const float* __restrict__ bias,
                                              float* __restrict__ outp) {
  const int t = threadIdx.x, l = t & 63, w = t >> 6;
  const int wr = w >> 1, wc = w & 1;
  const int bx = blockIdx.x, by = blockIdx.y;

  const unsigned short* a0 = Af + (((size_t)(bx * 8 + wr * 4) * 32) << 9) + l * 8;
  const unsigned short* b0 = Wf + (((size_t)(by * 4 + wc * 2) * 32) << 9) + l * 8;

  f32x4 acc[4][2];
#pragma unroll
  for (int m = 0; m < 4; ++m)
#pragma unroll
    for (int n = 0; n < 2; ++n) acc[m][n] = {0.f, 0.f, 0.f, 0.f};

#pragma unroll 4
  for (int c = 0; c < 32; ++c) {
    bf16x8 af[4], bfr[2];
#pragma unroll
    for (int m = 0; m < 4; ++m)
      af[m] = *(const bf16x8*)(a0 + (((size_t)(m * 32 + c)) << 9));
#pragma unroll
    for (int n = 0; n < 2; ++n)
      bfr[n] = *(const bf16x8*)(b0 + (((size_t)(n * 32 + c)) << 9));
#pragma unroll
    for (int n = 0; n < 2; ++n)
#pragma unroll
      for (int m = 0; m < 4; ++m)
        acc[m][n] = __builtin_amdgcn_mfma_f32_16x16x32_bf16(af[m], bfr[n], acc[m][n], 0, 0, 0);
  }

  const int l4 = (l >> 4) << 2, cl = l & 15;
#pragma unroll
  for (int n = 0; n < 2; ++n) {
    const int gc = by * 64 + wc * 32 + n * 16 + cl;
    const float bi = bias[gc];
#pragma unroll
    for (int m = 0; m < 4; ++m) {
      const int gr0 = bx * 128 + wr * 64 + m * 16 + l4;
#pragma unroll
      for (int j = 0; j < 4; ++j)
        outp[(size_t)(gr0 + j) * 1024 + gc] = acc[m][n][j] + bi;
    }
  }
}

// ---------------------------------------------------------------- attention v4 (unchanged from R4)
__global__ __launch_bounds__(512, 4) void attn_v4(const unsigned short* __restrict__ Qf,
                                                  const unsigned short* __restrict__ Kf,
                                                  const unsigned short* __restrict__ Vf,
                                                  const int* __restrict__ mask,
                                                  const int* __restrict__ flag,
                                                  float* __restrict__ Pout,
                                                  unsigned short* __restrict__ ctxf) {
  __shared__ float red[8 * 1024];   // 32 KB ctx cross-wave reduce
  __shared__ float rred[8][16];

  const int t = threadIdx.x, l = t & 63, w = t >> 6;
  const int bid = blockIdx.x;
  const int swz = (bid & 7) * 512 + (bid >> 3);   // bijective: 4096 % 8 == 0
  const int bh = swz >> 7, rt = swz & 127;
  const int q0 = rt * 16;
  const int g = l >> 4, q = l & 15;

  const unsigned short* qf = Qf + (size_t)bh * BH_ELEMS + l * 8;
  const unsigned short* kf = Kf + (size_t)bh * BH_ELEMS + l * 8;
  const unsigned short* vf = Vf + (size_t)bh * BH_ELEMS + l * 8;

  const bf16x8 aq0 = *(const bf16x8*)(qf + ((size_t)(rt * 2) << 9));
  const bf16x8 aq1 = *(const bf16x8*)(qf + ((size_t)(rt * 2 + 1) << 9));

  // ---- scores (swapped: A=K rows=k, B=Q cols=q)
  f32x4 sacc[16];
#pragma unroll
  for (int ct = 0; ct < 16; ++ct) {
    const int gi = w * 16 + ct;
    bf16x8 ak0 = *(const bf16x8*)(kf + ((size_t)(gi * 2) << 9));
    bf16x8 ak1 = *(const bf16x8*)(kf + ((size_t)(gi * 2 + 1) << 9));
    f32x4 s = {0.f, 0.f, 0.f, 0.f};
    s = __builtin_amdgcn_mfma_f32_16x16x32_bf16(ak0, aq0, s, 0, 0, 0);
    s = __builtin_amdgcn_mfma_f32_16x16x32_bf16(ak1, aq1, s, 0, 0, 0);
    sacc[ct] = s;
    if ((ct & 3) == 3) __builtin_amdgcn_sched_barrier(0);
  }

  // ---- mask slow path
  if (*flag == 0) {
#pragma unroll
    for (int ct = 0; ct < 16; ++ct) {
      const int col = w * 256 + ct * 16 + g * 4;
#pragma unroll
      for (int j = 0; j < 4; ++j)
        if (mask[(size_t)(q0 + q) * S + col + j] == 0) sacc[ct][j] = -1e9f;
    }
  }

  // ---- softmax over the lane's single row (scores pre-scaled by log2e)
  float m = -1e30f;
#pragma unroll
  for (int ct = 0; ct < 16; ++ct)
#pragma unroll
    for (int j = 0; j < 4; ++j) m = fmaxf(m, sacc[ct][j]);
  m = fmaxf(m, __shfl_xor(m, 16));
  m = fmaxf(m, __shfl_xor(m, 32));
  if (l < 16) rred[w][l] = m;
  __syncthreads();
  float mm = rred[0][q];
#pragma unroll
  for (int ww = 1; ww < 8; ++ww) mm = fmaxf(mm, rred[ww][q]);
  __syncthreads();

  float z = 0.f;
#pragma unroll
  for (int ct = 0; ct < 16; ++ct)
#pragma unroll
    for (int j = 0; j < 4; ++j) {
      float p = exp2f(sacc[ct][j] - mm);
      sacc[ct][j] = p;
      z += p;
    }
  z += __shfl_xor(z, 16);
  z += __shfl_xor(z, 32);
  if (l < 16) rred[w][l] = z;
  __syncthreads();
  float zz = rred[0][q];
#pragma unroll
  for (int ww = 1; ww < 8; ++ww) zz += rred[ww][q];
  const float inv = 1.0f / zz;

  // ---- normalize + vectorized nontemporal P store (row-contiguous)
  float* prow = Pout + ((size_t)bh * S + q0 + q) * S + w * 256 + g * 4;
#pragma unroll
  for (int ct = 0; ct < 16; ++ct) {
    f32x4 pn = sacc[ct] * inv;
    sacc[ct] = pn;
    __builtin_nontemporal_store(pn, (f32x4*)(prow + ct * 16));
  }

  // ---- pack ALL P -> bf16 A-frags in-register (butterfly); sacc dies here
  u32x4 pa[8];
#pragma unroll
  for (int ks = 0; ks < 8; ++ks) {
    const int t0 = ks * 2, t1 = t0 + 1;
    unsigned Xa, Xb, Ya, Yb;
    asm("v_cvt_pk_bf16_f32 %0, %1, %2" : "=v"(Xa) : "v"(sacc[t0][0]), "v"(sacc[t0][1]));
    asm("v_cvt_pk_bf16_f32 %0, %1, %2" : "=v"(Xb) : "v"(sacc[t0][2]), "v"(sacc[t0][3]));
    asm("v_cvt_pk_bf16_f32 %0, %1, %2" : "=v"(Ya) : "v"(sacc[t1][0]), "v"(sacc[t1][1]));
    asm("v_cvt_pk_bf16_f32 %0, %1, %2" : "=v"(Yb) : "v"(sacc[t1][2]), "v"(sacc[t1][3]));
    // butterfly round 1 (xor 32)
    const bool lo2 = (g < 2);
    unsigned sel_a = lo2 ? Ya : Xa, sel_b = lo2 ? Yb : Xb;
    unsigned kept_a = lo2 ? Xa : Ya, kept_b = lo2 ? Xb : Yb;
    unsigned r1_a = (unsigned)__shfl_xor((int)sel_a, 32);
    unsigned r1_b = (unsigned)__shfl_xor((int)sel_b, 32);
    // round 2 (xor 16): g1,g2 send kept; g0,g3 send r1.
    const bool mid = (g == 1) || (g == 2);
    unsigned s2_a = mid ? kept_a : r1_a;
    unsigned s2_b = mid ? kept_b : r1_b;
    unsigned r2_a = (unsigned)__shfl_xor((int)s2_a, 16);
    unsigned r2_b = (unsigned)__shfl_xor((int)s2_b, 16);
    // finals per group: g0:[kept,r2] g1:[r2,r1] g2:[r1,r2] g3:[r2,kept]
    u32x4 fr;
    fr[0] = (g == 0) ? kept_a : ((g == 2) ? r1_a : r2_a);
    fr[1] = (g == 0) ? kept_b : ((g == 2) ? r1_b : r2_b);
    fr[2] = (g == 3) ? kept_a : ((g == 1) ? r1_a : r2_a);
    fr[3] = (g == 3) ? kept_b : ((g == 1) ? r1_b : r2_b);
    pa[ks] = fr;
  }

  // ---- PV: pure MFMA stream (V-frag loads free to hoist into pack phase)
  f32x4 pacc[4];
#pragma unroll
  for (int n = 0; n < 4; ++n) pacc[n] = {0.f, 0.f, 0.f, 0.f};

  __builtin_amdgcn_s_setprio(1);
#pragma unroll
  for (int ks = 0; ks < 8; ++ks) {
    const bf16x8 ap = __builtin_bit_cast(bf16x8, pa[ks]);
    const int kbi = w * 8 + ks;
#pragma unroll
    for (int n = 0; n < 4; ++n) {
      bf16x8 bv = *(const bf16x8*)(vf + ((size_t)(kbi * 4 + n) << 9));
      pacc[n] = __builtin_amdgcn_mfma_f32_16x16x32_bf16(ap, bv, pacc[n], 0, 0, 0);
    }
  }
  __builtin_amdgcn_s_setprio(0);

  // ---- cross-wave K-slice reduce (f32 [8][1024]) -> ctx A-frag out
#pragma unroll
  for (int n = 0; n < 4; ++n)
#pragma unroll
    for (int j = 0; j < 4; ++j)
      red[w * 1024 + (g * 4 + j) * 64 + n * 16 + q] = pacc[n][j];
  __syncthreads();
  const int b = bh >> 4, h = bh & 15;
#pragma unroll
  for (int i = 0; i < 2; ++i) {
    int idx = t * 2 + i;
    float s = red[idx];
#pragma unroll
    for (int ww = 1; ww < 8; ++ww) s += red[ww * 1024 + idx];
    int qrow = idx >> 6, d = idx & 63;
    size_t addr = ((size_t)((b * 128 + rt) * 32 + h * 2 + (d >> 5)) << 9) +
                  (((d >> 3) & 3) << 7) + (qrow << 3) + (d & 7);
    ctxf[addr] = f2bf(s);
  }
}

// ---------------------------------------------------------------- launch
extern "C" void kernel_launch(void* const* d_in, const int* in_sizes, int n_in,
                              void* d_out, int out_size, void* d_ws, size_t ws_size,
                              hipStream_t stream) {
  const float* q = (const float*)d_in[0];
  const float* k = (const float*)d_in[1];
  const float* v = (const float*)d_in[2];
  const int* mask = (const int*)d_in[3];
  const float* w_q = (const float*)d_in[4];
  const float* b_q = (const float*)d_in[5];
  const float* w_k = (const float*)d_in[6];
  const float* b_k = (const float*)d_in[7];
  const float* w_v = (const float*)d_in[8];
  const float* b_v = (const float*)d_in[9];
  const float* w_o = (const float*)d_in[10];
  const float* b_o = (const float*)d_in[11];

  unsigned short* wsu = (unsigned short*)d_ws;
  unsigned short* A0 = wsu + 0 * A_ELEMS;  // qbf -> ctxf
  unsigned short* A1 = wsu + 1 * A_ELEMS;  // kbf
  unsigned short* A2 = wsu + 2 * A_ELEMS;  // vbf
  unsigned short* A3 = wsu + 3 * A_ELEMS;  // qhf
  unsigned short* Wb = wsu + 4 * A_ELEMS;  // wqf|wkf|wvf|wof
  unsigned short* wof = Wb + 3 * W_ELEMS;
  int* flag = (int*)(Wb + 4 * W_ELEMS);

  float* out_f = (float*)d_out;                  // [4096][1024] f32
  float* attnW = out_f + (size_t)4096 * 1024;    // [2][16][2048][2048] f32
  // khf/vhf scratch inside the (not-yet-final) `out` region:
  unsigned short* khf = (unsigned short*)d_out;          // 8.39 MB
  unsigned short* vhf = khf + A_ELEMS;                   // 8.39 MB

  hipMemsetAsync(flag, 0xFF, 4, stream);  // flag!=0 default; mask blocks AND to 0
  prologue_kernel<<<9216, 256, 0, stream>>>(q, k, v, w_q, w_k, w_v, w_o, mask,
                                            A0, Wb, flag);

  // qscale folds 1/sqrt(64) AND log2(e) (softmax done in exp2 domain).
  const float qscale = 0.125f * 1.4426950408889634f;
  proj_qkv<<<dim3(32, 16, 3), 256, 0, stream>>>(A0, Wb, b_q, b_k, b_v,
                                                A3, khf, vhf, qscale);

  attn_v4<<<4096, 512, 0, stream>>>(A3, khf, vhf, mask, flag, attnW, A0);

  proj_o<<<dim3(32, 16), 256, 0, stream>>>(A0, wof, b_o, out_f);
}